// Round 11
// baseline (70.678 us; speedup 1.0000x reference)
//
#include <hip/hip_runtime.h>
#include <hip/hip_fp16.h>

#define HL 32
#define WL 32
#define HH 512
#define WH 512
#define NB 12
#define NC 128
#define TH 16
#define TW 128
#define NRX 10             // x-cols: frac(fx)+127*31/511 -> x0-fx<=8, x1-fx<=9
#define NRY 3              // y-rows in footprint
#define NCELL (NRX*NRY*NB) // 360
#define LSTRIDE 17         // LDS cell stride in uint4 (16 data + 1 pad)
#define PLANE 262144       // HH*WH

typedef float f2_t __attribute__((ext_vector_type(2)));

// ---------------- kernel B: resize 512->32 bilinear+antialias -------------
__global__ __launch_bounds__(256) void k_down(const float* __restrict__ guide,
                                              float* __restrict__ luma_lr) {
  int o = blockIdx.x * 4 + (threadIdx.x >> 6);
  if (o >= 2 * HL * WL) return;
  int b = o >> 10;
  int r = o & 1023;
  int oy = r >> 5, ox = r & 31;
  int lane = threadIdx.x & 63;
  int ty = lane >> 1, xh = lane & 1;
  float posy = 16.f * oy + 7.5f;
  float posx = 16.f * ox + 7.5f;
  int jy = 16 * oy - 8 + ty;
  float wy = 0.f;
  if (jy >= 0 && jy < HH) wy = 1.f - fabsf((float)jy - posy) * (1.f / 16.f);
  int jyc = min(max(jy, 0), HH - 1);
  const float* row = guide + (size_t)b * 3 * PLANE + (size_t)jyc * WH;
  int jx0 = 16 * ox - 8 + xh * 16;
  float num = 0.f, wxs = 0.f;
#pragma unroll
  for (int g = 0; g < 4; ++g) {
    int jxb = jx0 + g * 4;
    int jxc = min(max(jxb, 0), WH - 4);
    float4 v0 = *(const float4*)(row + jxc);
    float4 v1 = *(const float4*)(row + PLANE + jxc);
    float4 v2 = *(const float4*)(row + 2 * PLANE + jxc);
#pragma unroll
    for (int k = 0; k < 4; ++k) {
      int jx = jxb + k;
      float wx = 0.f;
      if (jx >= 0 && jx < WH) wx = 1.f - fabsf((float)jx - posx) * (1.f / 16.f);
      float a = (k == 0) ? v0.x : (k == 1) ? v0.y : (k == 2) ? v0.z : v0.w;
      float bb = (k == 0) ? v1.x : (k == 1) ? v1.y : (k == 2) ? v1.z : v1.w;
      float c = (k == 0) ? v2.x : (k == 1) ? v2.y : (k == 2) ? v2.z : v2.w;
      num += wx * ((a + bb + c) * (1.0f / 3.0f));
      wxs += wx;
    }
  }
  float pn = wy * num;
  float pd = wy * wxs;
#pragma unroll
  for (int m = 1; m < 64; m <<= 1) {
    pn += __shfl_xor(pn, m);
    pd += __shfl_xor(pd, m);
  }
  if (lane == 0) luma_lr[o] = pn / pd;
}

// ---------------- kernel C: build box-filtered bilateral grid (fp16) ------
__global__ void k_grid(const float* __restrict__ feat, const float* __restrict__ luma_lr,
                       const float* __restrict__ sx_raw, const float* __restrict__ sy_raw,
                       const float* __restrict__ sr_raw, __half* __restrict__ gridh,
                       float* __restrict__ den) {
  int bid = blockIdx.x;                 // b*1024 + y*32 + x
  int b = bid >> 10;
  int yx = bid & 1023;
  int y = yx >> 5, x = yx & 31;
  __shared__ float wsm[NB * 9];
  int t = threadIdx.x;                  // 128 threads
  if (t < NB * 9) {
    int k = t / 9;
    int j = t - k * 9;
    int dy = j / 3 - 1, dx = (j % 3) - 1;
    int yy = y + dy, xx = x + dx;
    float wv = 0.f;
    if (yy >= 0 && yy < HL && xx >= 0 && xx < WL) {
      int p = yy * WL + xx;
      float lum = luma_lr[b * (HL * WL) + p];
      float dn = expf(sr_raw[p]) * 12.0f + 1e-5f;
      float d = fabsf(lum * 11.0f - (float)k);
      wv = fmaxf(1.0f - d / dn, 0.0f);
    }
    wsm[t] = wv;
  }
  __syncthreads();
  int p0 = y * WL + x;
  float scale = (1.0f + 0.01f * (expf(sx_raw[p0]) + expf(sy_raw[p0]))) * (1.0f / 9.0f);
  float scale1024 = scale * 1024.0f;
  float f[9];
  const float* fb = feat + ((size_t)(b * NC) + t) * (HL * WL);
#pragma unroll
  for (int j = 0; j < 9; ++j) {
    int dy = j / 3 - 1, dx = (j % 3) - 1;
    int yy = y + dy, xx = x + dx;
    f[j] = (yy >= 0 && yy < HL && xx >= 0 && xx < WL) ? fb[yy * WL + xx] : 0.f;
  }
#pragma unroll 1
  for (int z = 0; z < NB; ++z) {
    float acc = 0.f;
#pragma unroll
    for (int j = 0; j < 9; ++j) acc += f[j] * wsm[z * 9 + j];
    gridh[(size_t)(((b * NB + z) * HL + y) * WL + x) * NC + t] = __float2half(acc * scale1024);
  }
  if (t < NB) {
    float s = 0.f;
#pragma unroll
    for (int j = 0; j < 9; ++j) s += wsm[t * 9 + j];
    den[(size_t)(b * NB + t) * (HL * WL) + p0] = s * scale;
  }
}

// ---------------- kernel D: slice, 16x128 tile, 1024 thr, 512B store runs -
__global__ __launch_bounds__(1024) void k_slice(const uint4* __restrict__ grid4,
                                                const float* __restrict__ den,
                                                const float* __restrict__ guide,
                                                float* __restrict__ out) {
  __shared__ uint4 glds[NCELL * LSTRIDE];   // 360*17*16 = 97920 B
  __shared__ float denL[NCELL];             // 1440 B
  int bid = blockIdx.x;                 // 256 blocks: b(2) x th(32) x tw(4)
  int b = bid >> 7;
  int t = bid & 127;
  int th = t >> 2, tw = t & 3;
  int h0 = th * TH, w0 = tw * TW;
  int fy = (h0 * 31) / 511;
  int fx = (w0 * 31) / 511;
  int tid = threadIdx.x;

  // --- stage fp16 grid footprint: cellL = (ry*NRX+rx)*12 + z ---
#pragma unroll 1
  for (int i = tid; i < NCELL * 16; i += 1024) {
    int cellL = i >> 4, q = i & 15;
    int rr = cellL / 12;
    int z = cellL - rr * 12;
    int ry = rr / NRX, rx = rr - ry * NRX;
    int gy = min(fy + ry, HL - 1);
    int gx = min(fx + rx, WL - 1);
    glds[cellL * LSTRIDE + q] =
        grid4[(size_t)(((b * NB + z) * HL + gy) * WL + gx) * 16 + q];
  }
  if (tid < NCELL) {
    int rr = tid / 12;
    int z = tid - rr * 12;
    int ry = rr / NRX, rx = rr - ry * NRX;
    int gy = min(fy + ry, HL - 1);
    int gx = min(fx + rx, WL - 1);
    denL[tid] = den[(size_t)(b * NB + z) * (HL * WL) + gy * WL + gx];
  }
  __syncthreads();

  // --- per-pixel params: thread owns 2 adjacent px; 64 threads = 1 row ---
  const float SCC = 31.0f / 511.0f;
  int lh = tid >> 6;                 // 0..15
  int wp = (tid & 63) * 2;           // even w offset within tile
  int h = h0 + lh;
  float wk_[2][8];
  int off_[2][8];
  const float* gb0 = guide + (size_t)b * 3 * PLANE + (size_t)h * WH + w0 + wp;
  float2 g0 = *(const float2*)(gb0);
  float2 g1 = *(const float2*)(gb0 + PLANE);
  float2 g2 = *(const float2*)(gb0 + 2 * PLANE);
#pragma unroll
  for (int p = 0; p < 2; ++p) {
    int w = w0 + wp + p;
    float luma = ((p ? g0.y : g0.x) + (p ? g1.y : g1.x) + (p ? g2.y : g2.x)) * (1.0f / 3.0f);
    float u = fminf((float)w * SCC, 31.0f);
    float v = fminf((float)h * SCC, 31.0f);
    float wz = fminf(fmaxf(luma * 11.0f, 0.0f), 11.0f);
    int x0 = (int)u; float fxw = u - (float)x0; int x1 = min(x0 + 1, WL - 1);
    int y0 = (int)v; float fyw = v - (float)y0; int y1 = min(y0 + 1, HL - 1);
    int z0 = (int)wz; float fzw = wz - (float)z0; int z1 = min(z0 + 1, NB - 1);
    int rx0 = x0 - fx, rx1 = min(x1 - fx, NRX - 1);
    int ry0 = y0 - fy, ry1 = min(y1 - fy, NRY - 1);
    int c00 = (ry0 * NRX + rx0) * 12, c01 = (ry0 * NRX + rx1) * 12;
    int c10 = (ry1 * NRX + rx0) * 12, c11 = (ry1 * NRX + rx1) * 12;
    float x0w = 1.f - fxw, x1w = fxw;
    float y0w = 1.f - fyw, y1w = fyw;
    float z0w = 1.f - fzw, z1w = fzw;
    int idx[8] = {c00 + z0, c01 + z0, c10 + z0, c11 + z0,
                  c00 + z1, c01 + z1, c10 + z1, c11 + z1};
    float wt[8];
    wt[0] = z0w * y0w * x0w; wt[1] = z0w * y0w * x1w;
    wt[2] = z0w * y1w * x0w; wt[3] = z0w * y1w * x1w;
    wt[4] = z1w * y0w * x0w; wt[5] = z1w * y0w * x1w;
    wt[6] = z1w * y1w * x0w; wt[7] = z1w * y1w * x1w;
    float dv = 0.f;
#pragma unroll
    for (int k = 0; k < 8; ++k) dv += wt[k] * denL[idx[k]];
    float rinv = 1.0f / (1024.0f * fmaxf(dv, 1e-8f));
#pragma unroll
    for (int k = 0; k < 8; ++k) {
      wk_[p][k] = wt[k] * rinv;
      off_[p][k] = idx[k] * LSTRIDE;
    }
  }

  float* opb = out + ((size_t)(b * NC) << 18) + (size_t)h * WH + w0 + wp;
  // --- 16 channel-octets: 16 corner b128 reads (2 px), 8 f2 stores --------
#pragma unroll 2
  for (int cw = 0; cw < 16; ++cw) {
    float av[2][8];
#pragma unroll
    for (int p = 0; p < 2; ++p) {
#pragma unroll
      for (int c = 0; c < 8; ++c) av[p][c] = 0.f;
#pragma unroll
      for (int k = 0; k < 8; ++k) {
        uint4 q = glds[off_[p][k] + cw];
        const __half2* hp = (const __half2*)&q;
        float wkk = wk_[p][k];
        float2 f0 = __half22float2(hp[0]);
        float2 f1 = __half22float2(hp[1]);
        float2 f2 = __half22float2(hp[2]);
        float2 f3 = __half22float2(hp[3]);
        av[p][0] += wkk * f0.x; av[p][1] += wkk * f0.y;
        av[p][2] += wkk * f1.x; av[p][3] += wkk * f1.y;
        av[p][4] += wkk * f2.x; av[p][5] += wkk * f2.y;
        av[p][6] += wkk * f3.x; av[p][7] += wkk * f3.y;
      }
    }
    float* o0 = opb + ((size_t)(cw * 8) << 18);
#pragma unroll
    for (int c = 0; c < 8; ++c) {
      f2_t v2;
      v2.x = av[0][c];
      v2.y = av[1][c];
      *(f2_t*)(o0 + ((size_t)c << 18)) = v2;   // plain store: L2 aggregates
    }
  }
}

extern "C" void kernel_launch(void* const* d_in, const int* in_sizes, int n_in,
                              void* d_out, int out_size, void* d_ws, size_t ws_size,
                              hipStream_t stream) {
  const float* feat   = (const float*)d_in[0];  // (2,128,32,32)
  const float* guide  = (const float*)d_in[1];  // (2,3,512,512)
  const float* sx_raw = (const float*)d_in[2];  // (1,1,32,32)
  const float* sy_raw = (const float*)d_in[3];  // (1,1,32,32)
  // d_in[4] = th_raw: unused by the output
  const float* sr_raw = (const float*)d_in[5];  // (1,1,32,32)
  float* out = (float*)d_out;

  char* ws = (char*)d_ws;
  float*  luma_lr = (float*)ws;                         // 8 KB
  float*  den     = (float*)(ws + 8192);                // 96 KB
  __half* gridh   = (__half*)(ws + 8192 + 98304);       // 6 MB (16B aligned)

  k_down<<<512, 256, 0, stream>>>(guide, luma_lr);
  k_grid<<<2048, 128, 0, stream>>>(feat, luma_lr, sx_raw, sy_raw, sr_raw, gridh, den);
  k_slice<<<256, 1024, 0, stream>>>((const uint4*)gridh, den, guide, out);
}

// Round 12
// 68.247 us; speedup vs baseline: 1.0356x; 1.0356x over previous
//
#include <hip/hip_runtime.h>
#include <hip/hip_fp16.h>

#define HL 32
#define WL 32
#define HH 512
#define WH 512
#define NB 12
#define NC 128
#define TH 16
#define TW 64
#define NRX 6              // x-cols in footprint
#define NRY 3              // y-rows in footprint
#define NCELL (NRX*NRY*NB) // 216
#define LSTRIDE 17         // LDS cell stride in uint4 (16 data + 1 pad)
#define PLANE 262144       // HH*WH

// ---------------- kernel B: resize 512->32 bilinear+antialias -------------
__global__ __launch_bounds__(256) void k_down(const float* __restrict__ guide,
                                              float* __restrict__ luma_lr) {
  int o = blockIdx.x * 4 + (threadIdx.x >> 6);
  if (o >= 2 * HL * WL) return;
  int b = o >> 10;
  int r = o & 1023;
  int oy = r >> 5, ox = r & 31;
  int lane = threadIdx.x & 63;
  int ty = lane >> 1, xh = lane & 1;
  float posy = 16.f * oy + 7.5f;
  float posx = 16.f * ox + 7.5f;
  int jy = 16 * oy - 8 + ty;
  float wy = 0.f;
  if (jy >= 0 && jy < HH) wy = 1.f - fabsf((float)jy - posy) * (1.f / 16.f);
  int jyc = min(max(jy, 0), HH - 1);
  const float* row = guide + (size_t)b * 3 * PLANE + (size_t)jyc * WH;
  int jx0 = 16 * ox - 8 + xh * 16;
  float num = 0.f, wxs = 0.f;
#pragma unroll
  for (int g = 0; g < 4; ++g) {
    int jxb = jx0 + g * 4;
    int jxc = min(max(jxb, 0), WH - 4);
    float4 v0 = *(const float4*)(row + jxc);
    float4 v1 = *(const float4*)(row + PLANE + jxc);
    float4 v2 = *(const float4*)(row + 2 * PLANE + jxc);
#pragma unroll
    for (int k = 0; k < 4; ++k) {
      int jx = jxb + k;
      float wx = 0.f;
      if (jx >= 0 && jx < WH) wx = 1.f - fabsf((float)jx - posx) * (1.f / 16.f);
      float a = (k == 0) ? v0.x : (k == 1) ? v0.y : (k == 2) ? v0.z : v0.w;
      float bb = (k == 0) ? v1.x : (k == 1) ? v1.y : (k == 2) ? v1.z : v1.w;
      float c = (k == 0) ? v2.x : (k == 1) ? v2.y : (k == 2) ? v2.z : v2.w;
      num += wx * ((a + bb + c) * (1.0f / 3.0f));
      wxs += wx;
    }
  }
  float pn = wy * num;
  float pd = wy * wxs;
#pragma unroll
  for (int m = 1; m < 64; m <<= 1) {
    pn += __shfl_xor(pn, m);
    pd += __shfl_xor(pd, m);
  }
  if (lane == 0) luma_lr[o] = pn / pd;
}

// ---------------- kernel C: build box-filtered bilateral grid (fp16) ------
__global__ void k_grid(const float* __restrict__ feat, const float* __restrict__ luma_lr,
                       const float* __restrict__ sx_raw, const float* __restrict__ sy_raw,
                       const float* __restrict__ sr_raw, __half* __restrict__ gridh,
                       float* __restrict__ den) {
  int bid = blockIdx.x;                 // b*1024 + y*32 + x
  int b = bid >> 10;
  int yx = bid & 1023;
  int y = yx >> 5, x = yx & 31;
  __shared__ float wsm[NB * 9];
  int t = threadIdx.x;                  // 128 threads
  if (t < NB * 9) {
    int k = t / 9;
    int j = t - k * 9;
    int dy = j / 3 - 1, dx = (j % 3) - 1;
    int yy = y + dy, xx = x + dx;
    float wv = 0.f;
    if (yy >= 0 && yy < HL && xx >= 0 && xx < WL) {
      int p = yy * WL + xx;
      float lum = luma_lr[b * (HL * WL) + p];
      float dn = expf(sr_raw[p]) * 12.0f + 1e-5f;
      float d = fabsf(lum * 11.0f - (float)k);
      wv = fmaxf(1.0f - d / dn, 0.0f);
    }
    wsm[t] = wv;
  }
  __syncthreads();
  int p0 = y * WL + x;
  float scale = (1.0f + 0.01f * (expf(sx_raw[p0]) + expf(sy_raw[p0]))) * (1.0f / 9.0f);
  float scale1024 = scale * 1024.0f;
  float f[9];
  const float* fb = feat + ((size_t)(b * NC) + t) * (HL * WL);
#pragma unroll
  for (int j = 0; j < 9; ++j) {
    int dy = j / 3 - 1, dx = (j % 3) - 1;
    int yy = y + dy, xx = x + dx;
    f[j] = (yy >= 0 && yy < HL && xx >= 0 && xx < WL) ? fb[yy * WL + xx] : 0.f;
  }
#pragma unroll 1
  for (int z = 0; z < NB; ++z) {
    float acc = 0.f;
#pragma unroll
    for (int j = 0; j < 9; ++j) acc += f[j] * wsm[z * 9 + j];
    gridh[(size_t)(((b * NB + z) * HL + y) * WL + x) * NC + t] = __float2half(acc * scale1024);
  }
  if (t < NB) {
    float s = 0.f;
#pragma unroll
    for (int j = 0; j < 9; ++j) s += wsm[t * 9 + j];
    den[(size_t)(b * NB + t) * (HL * WL) + p0] = s * scale;
  }
}

// ---------------- kernel D: slice, 1 px/thread, 1024 thr, 32 waves/CU -----
__global__ __launch_bounds__(1024, 8) void k_slice(const uint4* __restrict__ grid4,
                                                   const float* __restrict__ den,
                                                   const float* __restrict__ guide,
                                                   float* __restrict__ out) {
  __shared__ uint4 glds[NCELL * LSTRIDE];   // 216*17*16 = 58752 B
  __shared__ float denL[NCELL];             // 864 B
  int bid = blockIdx.x;                 // 512 blocks: b(2) x th(32) x tw(8)
  int b = bid >> 8;
  int t = bid & 255;
  int th = t >> 3, tw = t & 7;
  int h0 = th * TH, w0 = tw * TW;
  int fy = (h0 * 31) / 511;
  int fx = (w0 * 31) / 511;
  int tid = threadIdx.x;

  // --- stage fp16 grid footprint: cellL = (ry*NRX+rx)*12 + z ---
#pragma unroll 1
  for (int i = tid; i < NCELL * 16; i += 1024) {
    int cellL = i >> 4, q = i & 15;
    int rr = cellL / 12;
    int z = cellL - rr * 12;
    int ry = rr / NRX, rx = rr - ry * NRX;
    int gy = min(fy + ry, HL - 1);
    int gx = min(fx + rx, WL - 1);
    glds[cellL * LSTRIDE + q] =
        grid4[(size_t)(((b * NB + z) * HL + gy) * WL + gx) * 16 + q];
  }
  if (tid < NCELL) {
    int rr = tid / 12;
    int z = tid - rr * 12;
    int ry = rr / NRX, rx = rr - ry * NRX;
    int gy = min(fy + ry, HL - 1);
    int gx = min(fx + rx, WL - 1);
    denL[tid] = den[(size_t)(b * NB + z) * (HL * WL) + gy * WL + gx];
  }
  __syncthreads();

  // --- per-pixel params: thread = pixel; 64 threads = one tile row ---
  const float SCC = 31.0f / 511.0f;
  int lh = tid >> 6;                 // 0..15
  int lw = tid & 63;
  int h = h0 + lh, w = w0 + lw;
  const float* gb0 = guide + (size_t)b * 3 * PLANE + (size_t)h * WH + w;
  float luma = (gb0[0] + gb0[PLANE] + gb0[2 * PLANE]) * (1.0f / 3.0f);
  float u = fminf((float)w * SCC, 31.0f);
  float v = fminf((float)h * SCC, 31.0f);
  float wz = fminf(fmaxf(luma * 11.0f, 0.0f), 11.0f);
  int x0 = (int)u; float fxw = u - (float)x0; int x1 = min(x0 + 1, WL - 1);
  int y0 = (int)v; float fyw = v - (float)y0; int y1 = min(y0 + 1, HL - 1);
  int z0 = (int)wz; float fzw = wz - (float)z0; int z1 = min(z0 + 1, NB - 1);
  int rx0 = x0 - fx, rx1 = min(x1 - fx, NRX - 1);
  int ry0 = y0 - fy, ry1 = min(y1 - fy, NRY - 1);
  int c00 = (ry0 * NRX + rx0) * 12, c01 = (ry0 * NRX + rx1) * 12;
  int c10 = (ry1 * NRX + rx0) * 12, c11 = (ry1 * NRX + rx1) * 12;
  float x0w = 1.f - fxw, x1w = fxw;
  float y0w = 1.f - fyw, y1w = fyw;
  float z0w = 1.f - fzw, z1w = fzw;
  int idx[8] = {c00 + z0, c01 + z0, c10 + z0, c11 + z0,
                c00 + z1, c01 + z1, c10 + z1, c11 + z1};
  float wt[8];
  wt[0] = z0w * y0w * x0w; wt[1] = z0w * y0w * x1w;
  wt[2] = z0w * y1w * x0w; wt[3] = z0w * y1w * x1w;
  wt[4] = z1w * y0w * x0w; wt[5] = z1w * y0w * x1w;
  wt[6] = z1w * y1w * x0w; wt[7] = z1w * y1w * x1w;
  float dv = 0.f;
#pragma unroll
  for (int k = 0; k < 8; ++k) dv += wt[k] * denL[idx[k]];
  float rinv = 1.0f / (1024.0f * fmaxf(dv, 1e-8f));
  float wk[8];
  int off[8];
#pragma unroll
  for (int k = 0; k < 8; ++k) {
    wk[k] = wt[k] * rinv;
    off[k] = idx[k] * LSTRIDE;
  }

  float* opb = out + ((size_t)(b * NC) << 18) + (size_t)h * WH + w;
  // --- 16 channel-octets: 8 corner b128 reads, 64 FMAs, 8 scalar stores ---
#pragma unroll 1
  for (int cw = 0; cw < 16; ++cw) {
    float a0 = 0.f, a1 = 0.f, a2 = 0.f, a3 = 0.f, a4 = 0.f, a5 = 0.f, a6 = 0.f, a7 = 0.f;
#pragma unroll
    for (int k = 0; k < 8; ++k) {
      uint4 q = glds[off[k] + cw];
      const __half2* hp = (const __half2*)&q;
      float wkk = wk[k];
      float2 f0 = __half22float2(hp[0]);
      float2 f1 = __half22float2(hp[1]);
      float2 f2 = __half22float2(hp[2]);
      float2 f3 = __half22float2(hp[3]);
      a0 += wkk * f0.x; a1 += wkk * f0.y;
      a2 += wkk * f1.x; a3 += wkk * f1.y;
      a4 += wkk * f2.x; a5 += wkk * f2.y;
      a6 += wkk * f3.x; a7 += wkk * f3.y;
    }
    float* o0 = opb + ((size_t)(cw * 8) << 18);
    o0[0] = a0;
    o0[(size_t)1 << 18] = a1;
    o0[(size_t)2 << 18] = a2;
    o0[(size_t)3 << 18] = a3;
    o0[(size_t)4 << 18] = a4;
    o0[(size_t)5 << 18] = a5;
    o0[(size_t)6 << 18] = a6;
    o0[(size_t)7 << 18] = a7;
  }
}

extern "C" void kernel_launch(void* const* d_in, const int* in_sizes, int n_in,
                              void* d_out, int out_size, void* d_ws, size_t ws_size,
                              hipStream_t stream) {
  const float* feat   = (const float*)d_in[0];  // (2,128,32,32)
  const float* guide  = (const float*)d_in[1];  // (2,3,512,512)
  const float* sx_raw = (const float*)d_in[2];  // (1,1,32,32)
  const float* sy_raw = (const float*)d_in[3];  // (1,1,32,32)
  // d_in[4] = th_raw: unused by the output
  const float* sr_raw = (const float*)d_in[5];  // (1,1,32,32)
  float* out = (float*)d_out;

  char* ws = (char*)d_ws;
  float*  luma_lr = (float*)ws;                         // 8 KB
  float*  den     = (float*)(ws + 8192);                // 96 KB
  __half* gridh   = (__half*)(ws + 8192 + 98304);       // 6 MB (16B aligned)

  k_down<<<512, 256, 0, stream>>>(guide, luma_lr);
  k_grid<<<2048, 128, 0, stream>>>(feat, luma_lr, sx_raw, sy_raw, sr_raw, gridh, den);
  k_slice<<<512, 1024, 0, stream>>>((const uint4*)gridh, den, guide, out);
}

// Round 13
// 65.995 us; speedup vs baseline: 1.0710x; 1.0341x over previous
//
#include <hip/hip_runtime.h>
#include <hip/hip_fp16.h>

#define HL 32
#define WL 32
#define HH 512
#define WH 512
#define NB 12
#define NC 128
#define TH 16
#define TW 64
#define NRX 6              // x-cols in footprint
#define NRY 3              // y-rows in footprint
#define NCELL (NRX*NRY*NB) // 216
#define LSTRIDE 17         // LDS cell stride in uint4 (16 data + 1 pad)
#define PLANE 262144       // HH*WH

// ---------------- kernel B: resize 512->32 bilinear+antialias -------------
__global__ __launch_bounds__(256) void k_down(const float* __restrict__ guide,
                                              float* __restrict__ luma_lr) {
  int o = blockIdx.x * 4 + (threadIdx.x >> 6);
  if (o >= 2 * HL * WL) return;
  int b = o >> 10;
  int r = o & 1023;
  int oy = r >> 5, ox = r & 31;
  int lane = threadIdx.x & 63;
  int ty = lane >> 1, xh = lane & 1;
  float posy = 16.f * oy + 7.5f;
  float posx = 16.f * ox + 7.5f;
  int jy = 16 * oy - 8 + ty;
  float wy = 0.f;
  if (jy >= 0 && jy < HH) wy = 1.f - fabsf((float)jy - posy) * (1.f / 16.f);
  int jyc = min(max(jy, 0), HH - 1);
  const float* row = guide + (size_t)b * 3 * PLANE + (size_t)jyc * WH;
  int jx0 = 16 * ox - 8 + xh * 16;
  float num = 0.f, wxs = 0.f;
#pragma unroll
  for (int g = 0; g < 4; ++g) {
    int jxb = jx0 + g * 4;
    int jxc = min(max(jxb, 0), WH - 4);
    float4 v0 = *(const float4*)(row + jxc);
    float4 v1 = *(const float4*)(row + PLANE + jxc);
    float4 v2 = *(const float4*)(row + 2 * PLANE + jxc);
#pragma unroll
    for (int k = 0; k < 4; ++k) {
      int jx = jxb + k;
      float wx = 0.f;
      if (jx >= 0 && jx < WH) wx = 1.f - fabsf((float)jx - posx) * (1.f / 16.f);
      float a = (k == 0) ? v0.x : (k == 1) ? v0.y : (k == 2) ? v0.z : v0.w;
      float bb = (k == 0) ? v1.x : (k == 1) ? v1.y : (k == 2) ? v1.z : v1.w;
      float c = (k == 0) ? v2.x : (k == 1) ? v2.y : (k == 2) ? v2.z : v2.w;
      num += wx * ((a + bb + c) * (1.0f / 3.0f));
      wxs += wx;
    }
  }
  float pn = wy * num;
  float pd = wy * wxs;
#pragma unroll
  for (int m = 1; m < 64; m <<= 1) {
    pn += __shfl_xor(pn, m);
    pd += __shfl_xor(pd, m);
  }
  if (lane == 0) luma_lr[o] = pn / pd;
}

// ---------------- kernel C: build box-filtered bilateral grid (fp16) ------
__global__ void k_grid(const float* __restrict__ feat, const float* __restrict__ luma_lr,
                       const float* __restrict__ sx_raw, const float* __restrict__ sy_raw,
                       const float* __restrict__ sr_raw, __half* __restrict__ gridh,
                       float* __restrict__ den) {
  int bid = blockIdx.x;                 // b*1024 + y*32 + x
  int b = bid >> 10;
  int yx = bid & 1023;
  int y = yx >> 5, x = yx & 31;
  __shared__ float wsm[NB * 9];
  int t = threadIdx.x;                  // 128 threads
  if (t < NB * 9) {
    int k = t / 9;
    int j = t - k * 9;
    int dy = j / 3 - 1, dx = (j % 3) - 1;
    int yy = y + dy, xx = x + dx;
    float wv = 0.f;
    if (yy >= 0 && yy < HL && xx >= 0 && xx < WL) {
      int p = yy * WL + xx;
      float lum = luma_lr[b * (HL * WL) + p];
      float dn = expf(sr_raw[p]) * 12.0f + 1e-5f;
      float d = fabsf(lum * 11.0f - (float)k);
      wv = fmaxf(1.0f - d / dn, 0.0f);
    }
    wsm[t] = wv;
  }
  __syncthreads();
  int p0 = y * WL + x;
  float scale = (1.0f + 0.01f * (expf(sx_raw[p0]) + expf(sy_raw[p0]))) * (1.0f / 9.0f);
  float scale1024 = scale * 1024.0f;
  float f[9];
  const float* fb = feat + ((size_t)(b * NC) + t) * (HL * WL);
#pragma unroll
  for (int j = 0; j < 9; ++j) {
    int dy = j / 3 - 1, dx = (j % 3) - 1;
    int yy = y + dy, xx = x + dx;
    f[j] = (yy >= 0 && yy < HL && xx >= 0 && xx < WL) ? fb[yy * WL + xx] : 0.f;
  }
#pragma unroll 1
  for (int z = 0; z < NB; ++z) {
    float acc = 0.f;
#pragma unroll
    for (int j = 0; j < 9; ++j) acc += f[j] * wsm[z * 9 + j];
    gridh[(size_t)(((b * NB + z) * HL + y) * WL + x) * NC + t] = __float2half(acc * scale1024);
  }
  if (t < NB) {
    float s = 0.f;
#pragma unroll
    for (int j = 0; j < 9; ++j) s += wsm[t * 9 + j];
    den[(size_t)(b * NB + t) * (HL * WL) + p0] = s * scale;
  }
}

// ---------------- kernel D: slice, 2-deep cw ping-pong pipeline -----------
__global__ __launch_bounds__(1024, 4) void k_slice(const uint4* __restrict__ grid4,
                                                   const float* __restrict__ den,
                                                   const float* __restrict__ guide,
                                                   float* __restrict__ out) {
  __shared__ uint4 glds[NCELL * LSTRIDE];   // 216*17*16 = 58752 B
  __shared__ float denL[NCELL];             // 864 B
  int bid = blockIdx.x;                 // 512 blocks: b(2) x th(32) x tw(8)
  int b = bid >> 8;
  int t = bid & 255;
  int th = t >> 3, tw = t & 7;
  int h0 = th * TH, w0 = tw * TW;
  int fy = (h0 * 31) / 511;
  int fx = (w0 * 31) / 511;
  int tid = threadIdx.x;

  // --- stage fp16 grid footprint: cellL = (ry*NRX+rx)*12 + z ---
#pragma unroll 1
  for (int i = tid; i < NCELL * 16; i += 1024) {
    int cellL = i >> 4, q = i & 15;
    int rr = cellL / 12;
    int z = cellL - rr * 12;
    int ry = rr / NRX, rx = rr - ry * NRX;
    int gy = min(fy + ry, HL - 1);
    int gx = min(fx + rx, WL - 1);
    glds[cellL * LSTRIDE + q] =
        grid4[(size_t)(((b * NB + z) * HL + gy) * WL + gx) * 16 + q];
  }
  if (tid < NCELL) {
    int rr = tid / 12;
    int z = tid - rr * 12;
    int ry = rr / NRX, rx = rr - ry * NRX;
    int gy = min(fy + ry, HL - 1);
    int gx = min(fx + rx, WL - 1);
    denL[tid] = den[(size_t)(b * NB + z) * (HL * WL) + gy * WL + gx];
  }
  __syncthreads();

  // --- per-pixel params: thread = pixel; 64 threads = one tile row ---
  const float SCC = 31.0f / 511.0f;
  int lh = tid >> 6;                 // 0..15
  int lw = tid & 63;
  int h = h0 + lh, w = w0 + lw;
  const float* gb0 = guide + (size_t)b * 3 * PLANE + (size_t)h * WH + w;
  float luma = (gb0[0] + gb0[PLANE] + gb0[2 * PLANE]) * (1.0f / 3.0f);
  float u = fminf((float)w * SCC, 31.0f);
  float v = fminf((float)h * SCC, 31.0f);
  float wz = fminf(fmaxf(luma * 11.0f, 0.0f), 11.0f);
  int x0 = (int)u; float fxw = u - (float)x0; int x1 = min(x0 + 1, WL - 1);
  int y0 = (int)v; float fyw = v - (float)y0; int y1 = min(y0 + 1, HL - 1);
  int z0 = (int)wz; float fzw = wz - (float)z0; int z1 = min(z0 + 1, NB - 1);
  int rx0 = x0 - fx, rx1 = min(x1 - fx, NRX - 1);
  int ry0 = y0 - fy, ry1 = min(y1 - fy, NRY - 1);
  int c00 = (ry0 * NRX + rx0) * 12, c01 = (ry0 * NRX + rx1) * 12;
  int c10 = (ry1 * NRX + rx0) * 12, c11 = (ry1 * NRX + rx1) * 12;
  float x0w = 1.f - fxw, x1w = fxw;
  float y0w = 1.f - fyw, y1w = fyw;
  float z0w = 1.f - fzw, z1w = fzw;
  int idx[8] = {c00 + z0, c01 + z0, c10 + z0, c11 + z0,
                c00 + z1, c01 + z1, c10 + z1, c11 + z1};
  float wt[8];
  wt[0] = z0w * y0w * x0w; wt[1] = z0w * y0w * x1w;
  wt[2] = z0w * y1w * x0w; wt[3] = z0w * y1w * x1w;
  wt[4] = z1w * y0w * x0w; wt[5] = z1w * y0w * x1w;
  wt[6] = z1w * y1w * x0w; wt[7] = z1w * y1w * x1w;
  float dv = 0.f;
#pragma unroll
  for (int k = 0; k < 8; ++k) dv += wt[k] * denL[idx[k]];
  float rinv = 1.0f / (1024.0f * fmaxf(dv, 1e-8f));
  float wk[8];
  int off[8];
#pragma unroll
  for (int k = 0; k < 8; ++k) {
    wk[k] = wt[k] * rinv;
    off[k] = idx[k] * LSTRIDE;
  }

  float* opb = out + ((size_t)(b * NC) << 18) + (size_t)h * WH + w;

  // --- 16 channel-octets, 2-deep register ping-pong over cw ---
  uint4 qA[8], qB[8];
#pragma unroll
  for (int k = 0; k < 8; ++k) qA[k] = glds[off[k] + 0];

#define COMPUTE_STORE(QBUF, CW)                                              \
  {                                                                          \
    float a0 = 0.f, a1 = 0.f, a2 = 0.f, a3 = 0.f,                            \
          a4 = 0.f, a5 = 0.f, a6 = 0.f, a7 = 0.f;                            \
    _Pragma("unroll")                                                        \
    for (int k = 0; k < 8; ++k) {                                            \
      const __half2* hp = (const __half2*)&QBUF[k];                          \
      float wkk = wk[k];                                                     \
      float2 f0 = __half22float2(hp[0]);                                     \
      float2 f1 = __half22float2(hp[1]);                                     \
      float2 f2 = __half22float2(hp[2]);                                     \
      float2 f3 = __half22float2(hp[3]);                                     \
      a0 += wkk * f0.x; a1 += wkk * f0.y;                                    \
      a2 += wkk * f1.x; a3 += wkk * f1.y;                                    \
      a4 += wkk * f2.x; a5 += wkk * f2.y;                                    \
      a6 += wkk * f3.x; a7 += wkk * f3.y;                                    \
    }                                                                        \
    float* o0 = opb + ((size_t)((CW) * 8) << 18);                            \
    o0[0] = a0;                                                              \
    o0[(size_t)1 << 18] = a1;                                                \
    o0[(size_t)2 << 18] = a2;                                                \
    o0[(size_t)3 << 18] = a3;                                                \
    o0[(size_t)4 << 18] = a4;                                                \
    o0[(size_t)5 << 18] = a5;                                                \
    o0[(size_t)6 << 18] = a6;                                                \
    o0[(size_t)7 << 18] = a7;                                                \
  }

#pragma unroll 1
  for (int cwp = 0; cwp < 8; ++cwp) {
    int cwA = cwp * 2, cwB = cwp * 2 + 1;
#pragma unroll
    for (int k = 0; k < 8; ++k) qB[k] = glds[off[k] + cwB];   // prefetch B
    COMPUTE_STORE(qA, cwA);
    if (cwp < 7) {
#pragma unroll
      for (int k = 0; k < 8; ++k) qA[k] = glds[off[k] + cwB + 1]; // prefetch next A
    }
    COMPUTE_STORE(qB, cwB);
  }
#undef COMPUTE_STORE
}

extern "C" void kernel_launch(void* const* d_in, const int* in_sizes, int n_in,
                              void* d_out, int out_size, void* d_ws, size_t ws_size,
                              hipStream_t stream) {
  const float* feat   = (const float*)d_in[0];  // (2,128,32,32)
  const float* guide  = (const float*)d_in[1];  // (2,3,512,512)
  const float* sx_raw = (const float*)d_in[2];  // (1,1,32,32)
  const float* sy_raw = (const float*)d_in[3];  // (1,1,32,32)
  // d_in[4] = th_raw: unused by the output
  const float* sr_raw = (const float*)d_in[5];  // (1,1,32,32)
  float* out = (float*)d_out;

  char* ws = (char*)d_ws;
  float*  luma_lr = (float*)ws;                         // 8 KB
  float*  den     = (float*)(ws + 8192);                // 96 KB
  __half* gridh   = (__half*)(ws + 8192 + 98304);       // 6 MB (16B aligned)

  k_down<<<512, 256, 0, stream>>>(guide, luma_lr);
  k_grid<<<2048, 128, 0, stream>>>(feat, luma_lr, sx_raw, sy_raw, sr_raw, gridh, den);
  k_slice<<<512, 1024, 0, stream>>>((const uint4*)gridh, den, guide, out);
}

// Round 14
// 65.324 us; speedup vs baseline: 1.0820x; 1.0103x over previous
//
#include <hip/hip_runtime.h>
#include <hip/hip_fp16.h>

#define HL 32
#define WL 32
#define HH 512
#define WH 512
#define NB 12
#define NC 128
#define TH 16
#define TW 64
#define NRX 6              // x-cols in footprint
#define NRY 3              // y-rows in footprint
#define NCELL (NRX*NRY*NB) // 216
#define LSTRIDE 17         // LDS cell stride in uint4 (16 data + 1 pad)
#define PLANE 262144       // HH*WH

// ---------------- kernel T: transpose feat [b][c][y][x] -> [b][y][x][c] ---
__global__ __launch_bounds__(256) void k_tr(const float* __restrict__ feat,
                                            float* __restrict__ feat_t) {
  int i = blockIdx.x * 256 + threadIdx.x;     // 2*32*32*128 = 262144
  if (i >= 2 * HL * WL * NC) return;
  int c = i & 127;
  int pix = (i >> 7) & 1023;
  int b = i >> 17;
  feat_t[i] = feat[((size_t)(b * NC + c) << 10) + pix];  // dst coalesced
}

// ---------------- kernel B: resize 512->32 bilinear+antialias -------------
__global__ __launch_bounds__(256) void k_down(const float* __restrict__ guide,
                                              float* __restrict__ luma_lr) {
  int o = blockIdx.x * 4 + (threadIdx.x >> 6);
  if (o >= 2 * HL * WL) return;
  int b = o >> 10;
  int r = o & 1023;
  int oy = r >> 5, ox = r & 31;
  int lane = threadIdx.x & 63;
  int ty = lane >> 1, xh = lane & 1;
  float posy = 16.f * oy + 7.5f;
  float posx = 16.f * ox + 7.5f;
  int jy = 16 * oy - 8 + ty;
  float wy = 0.f;
  if (jy >= 0 && jy < HH) wy = 1.f - fabsf((float)jy - posy) * (1.f / 16.f);
  int jyc = min(max(jy, 0), HH - 1);
  const float* row = guide + (size_t)b * 3 * PLANE + (size_t)jyc * WH;
  int jx0 = 16 * ox - 8 + xh * 16;
  float num = 0.f, wxs = 0.f;
#pragma unroll
  for (int g = 0; g < 4; ++g) {
    int jxb = jx0 + g * 4;
    int jxc = min(max(jxb, 0), WH - 4);
    float4 v0 = *(const float4*)(row + jxc);
    float4 v1 = *(const float4*)(row + PLANE + jxc);
    float4 v2 = *(const float4*)(row + 2 * PLANE + jxc);
#pragma unroll
    for (int k = 0; k < 4; ++k) {
      int jx = jxb + k;
      float wx = 0.f;
      if (jx >= 0 && jx < WH) wx = 1.f - fabsf((float)jx - posx) * (1.f / 16.f);
      float a = (k == 0) ? v0.x : (k == 1) ? v0.y : (k == 2) ? v0.z : v0.w;
      float bb = (k == 0) ? v1.x : (k == 1) ? v1.y : (k == 2) ? v1.z : v1.w;
      float c = (k == 0) ? v2.x : (k == 1) ? v2.y : (k == 2) ? v2.z : v2.w;
      num += wx * ((a + bb + c) * (1.0f / 3.0f));
      wxs += wx;
    }
  }
  float pn = wy * num;
  float pd = wy * wxs;
#pragma unroll
  for (int m = 1; m < 64; m <<= 1) {
    pn += __shfl_xor(pn, m);
    pd += __shfl_xor(pd, m);
  }
  if (lane == 0) luma_lr[o] = pn / pd;
}

// ---------------- kernel C: build box-filtered bilateral grid (fp16) ------
// feat_t[b][y][x][c]: lane t = channel -> all 9 loads coalesced (512B runs).
__global__ void k_grid(const float* __restrict__ feat_t, const float* __restrict__ luma_lr,
                       const float* __restrict__ sx_raw, const float* __restrict__ sy_raw,
                       const float* __restrict__ sr_raw, __half* __restrict__ gridh,
                       float* __restrict__ den) {
  int bid = blockIdx.x;                 // b*1024 + y*32 + x
  int b = bid >> 10;
  int yx = bid & 1023;
  int y = yx >> 5, x = yx & 31;
  __shared__ float wsm[NB * 9];
  int t = threadIdx.x;                  // 128 threads
  if (t < NB * 9) {
    int k = t / 9;
    int j = t - k * 9;
    int dy = j / 3 - 1, dx = (j % 3) - 1;
    int yy = y + dy, xx = x + dx;
    float wv = 0.f;
    if (yy >= 0 && yy < HL && xx >= 0 && xx < WL) {
      int p = yy * WL + xx;
      float lum = luma_lr[b * (HL * WL) + p];
      float dn = expf(sr_raw[p]) * 12.0f + 1e-5f;
      float d = fabsf(lum * 11.0f - (float)k);
      wv = fmaxf(1.0f - d / dn, 0.0f);
    }
    wsm[t] = wv;
  }
  __syncthreads();
  int p0 = y * WL + x;
  float scale = (1.0f + 0.01f * (expf(sx_raw[p0]) + expf(sy_raw[p0]))) * (1.0f / 9.0f);
  float scale1024 = scale * 1024.0f;
  float f[9];
  const float* fb = feat_t + ((size_t)b << 17);   // b*32*32*128
#pragma unroll
  for (int j = 0; j < 9; ++j) {
    int dy = j / 3 - 1, dx = (j % 3) - 1;
    int yy = y + dy, xx = x + dx;
    f[j] = (yy >= 0 && yy < HL && xx >= 0 && xx < WL)
               ? fb[(size_t)(yy * WL + xx) * NC + t] : 0.f;
  }
#pragma unroll 1
  for (int z = 0; z < NB; ++z) {
    float acc = 0.f;
#pragma unroll
    for (int j = 0; j < 9; ++j) acc += f[j] * wsm[z * 9 + j];
    gridh[(size_t)(((b * NB + z) * HL + y) * WL + x) * NC + t] = __float2half(acc * scale1024);
  }
  if (t < NB) {
    float s = 0.f;
#pragma unroll
    for (int j = 0; j < 9; ++j) s += wsm[t * 9 + j];
    den[(size_t)(b * NB + t) * (HL * WL) + p0] = s * scale;
  }
}

// ---------------- kernel D: slice, 2-deep cw ping-pong pipeline -----------
__global__ __launch_bounds__(1024, 4) void k_slice(const uint4* __restrict__ grid4,
                                                   const float* __restrict__ den,
                                                   const float* __restrict__ guide,
                                                   float* __restrict__ out) {
  __shared__ uint4 glds[NCELL * LSTRIDE];   // 216*17*16 = 58752 B
  __shared__ float denL[NCELL];             // 864 B
  int bid = blockIdx.x;                 // 512 blocks: b(2) x th(32) x tw(8)
  int b = bid >> 8;
  int t = bid & 255;
  int th = t >> 3, tw = t & 7;
  int h0 = th * TH, w0 = tw * TW;
  int fy = (h0 * 31) / 511;
  int fx = (w0 * 31) / 511;
  int tid = threadIdx.x;

  // --- stage fp16 grid footprint: cellL = (ry*NRX+rx)*12 + z ---
#pragma unroll 1
  for (int i = tid; i < NCELL * 16; i += 1024) {
    int cellL = i >> 4, q = i & 15;
    int rr = cellL / 12;
    int z = cellL - rr * 12;
    int ry = rr / NRX, rx = rr - ry * NRX;
    int gy = min(fy + ry, HL - 1);
    int gx = min(fx + rx, WL - 1);
    glds[cellL * LSTRIDE + q] =
        grid4[(size_t)(((b * NB + z) * HL + gy) * WL + gx) * 16 + q];
  }
  if (tid < NCELL) {
    int rr = tid / 12;
    int z = tid - rr * 12;
    int ry = rr / NRX, rx = rr - ry * NRX;
    int gy = min(fy + ry, HL - 1);
    int gx = min(fx + rx, WL - 1);
    denL[tid] = den[(size_t)(b * NB + z) * (HL * WL) + gy * WL + gx];
  }
  __syncthreads();

  // --- per-pixel params: thread = pixel; 64 threads = one tile row ---
  const float SCC = 31.0f / 511.0f;
  int lh = tid >> 6;                 // 0..15
  int lw = tid & 63;
  int h = h0 + lh, w = w0 + lw;
  const float* gb0 = guide + (size_t)b * 3 * PLANE + (size_t)h * WH + w;
  float luma = (gb0[0] + gb0[PLANE] + gb0[2 * PLANE]) * (1.0f / 3.0f);
  float u = fminf((float)w * SCC, 31.0f);
  float v = fminf((float)h * SCC, 31.0f);
  float wz = fminf(fmaxf(luma * 11.0f, 0.0f), 11.0f);
  int x0 = (int)u; float fxw = u - (float)x0; int x1 = min(x0 + 1, WL - 1);
  int y0 = (int)v; float fyw = v - (float)y0; int y1 = min(y0 + 1, HL - 1);
  int z0 = (int)wz; float fzw = wz - (float)z0; int z1 = min(z0 + 1, NB - 1);
  int rx0 = x0 - fx, rx1 = min(x1 - fx, NRX - 1);
  int ry0 = y0 - fy, ry1 = min(y1 - fy, NRY - 1);
  int c00 = (ry0 * NRX + rx0) * 12, c01 = (ry0 * NRX + rx1) * 12;
  int c10 = (ry1 * NRX + rx0) * 12, c11 = (ry1 * NRX + rx1) * 12;
  float x0w = 1.f - fxw, x1w = fxw;
  float y0w = 1.f - fyw, y1w = fyw;
  float z0w = 1.f - fzw, z1w = fzw;
  int idx[8] = {c00 + z0, c01 + z0, c10 + z0, c11 + z0,
                c00 + z1, c01 + z1, c10 + z1, c11 + z1};
  float wt[8];
  wt[0] = z0w * y0w * x0w; wt[1] = z0w * y0w * x1w;
  wt[2] = z0w * y1w * x0w; wt[3] = z0w * y1w * x1w;
  wt[4] = z1w * y0w * x0w; wt[5] = z1w * y0w * x1w;
  wt[6] = z1w * y1w * x0w; wt[7] = z1w * y1w * x1w;
  float dv = 0.f;
#pragma unroll
  for (int k = 0; k < 8; ++k) dv += wt[k] * denL[idx[k]];
  float rinv = 1.0f / (1024.0f * fmaxf(dv, 1e-8f));
  float wk[8];
  int off[8];
#pragma unroll
  for (int k = 0; k < 8; ++k) {
    wk[k] = wt[k] * rinv;
    off[k] = idx[k] * LSTRIDE;
  }

  float* opb = out + ((size_t)(b * NC) << 18) + (size_t)h * WH + w;

  // --- 16 channel-octets, 2-deep register ping-pong over cw ---
  uint4 qA[8], qB[8];
#pragma unroll
  for (int k = 0; k < 8; ++k) qA[k] = glds[off[k] + 0];

#define COMPUTE_STORE(QBUF, CW)                                              \
  {                                                                          \
    float a0 = 0.f, a1 = 0.f, a2 = 0.f, a3 = 0.f,                            \
          a4 = 0.f, a5 = 0.f, a6 = 0.f, a7 = 0.f;                            \
    _Pragma("unroll")                                                        \
    for (int k = 0; k < 8; ++k) {                                            \
      const __half2* hp = (const __half2*)&QBUF[k];                          \
      float wkk = wk[k];                                                     \
      float2 f0 = __half22float2(hp[0]);                                     \
      float2 f1 = __half22float2(hp[1]);                                     \
      float2 f2 = __half22float2(hp[2]);                                     \
      float2 f3 = __half22float2(hp[3]);                                     \
      a0 += wkk * f0.x; a1 += wkk * f0.y;                                    \
      a2 += wkk * f1.x; a3 += wkk * f1.y;                                    \
      a4 += wkk * f2.x; a5 += wkk * f2.y;                                    \
      a6 += wkk * f3.x; a7 += wkk * f3.y;                                    \
    }                                                                        \
    float* o0 = opb + ((size_t)((CW) * 8) << 18);                            \
    o0[0] = a0;                                                              \
    o0[(size_t)1 << 18] = a1;                                                \
    o0[(size_t)2 << 18] = a2;                                                \
    o0[(size_t)3 << 18] = a3;                                                \
    o0[(size_t)4 << 18] = a4;                                                \
    o0[(size_t)5 << 18] = a5;                                                \
    o0[(size_t)6 << 18] = a6;                                                \
    o0[(size_t)7 << 18] = a7;                                                \
  }

#pragma unroll 1
  for (int cwp = 0; cwp < 8; ++cwp) {
    int cwA = cwp * 2, cwB = cwp * 2 + 1;
#pragma unroll
    for (int k = 0; k < 8; ++k) qB[k] = glds[off[k] + cwB];   // prefetch B
    COMPUTE_STORE(qA, cwA);
    if (cwp < 7) {
#pragma unroll
      for (int k = 0; k < 8; ++k) qA[k] = glds[off[k] + cwB + 1]; // prefetch next A
    }
    COMPUTE_STORE(qB, cwB);
  }
#undef COMPUTE_STORE
}

extern "C" void kernel_launch(void* const* d_in, const int* in_sizes, int n_in,
                              void* d_out, int out_size, void* d_ws, size_t ws_size,
                              hipStream_t stream) {
  const float* feat   = (const float*)d_in[0];  // (2,128,32,32)
  const float* guide  = (const float*)d_in[1];  // (2,3,512,512)
  const float* sx_raw = (const float*)d_in[2];  // (1,1,32,32)
  const float* sy_raw = (const float*)d_in[3];  // (1,1,32,32)
  // d_in[4] = th_raw: unused by the output
  const float* sr_raw = (const float*)d_in[5];  // (1,1,32,32)
  float* out = (float*)d_out;

  char* ws = (char*)d_ws;
  float*  luma_lr = (float*)ws;                         // 8 KB
  float*  den     = (float*)(ws + 8192);                // 96 KB
  __half* gridh   = (__half*)(ws + 8192 + 98304);       // 6 MB
  float*  feat_t  = (float*)(ws + 8192 + 98304 + 6291456); // 4 MB

  k_tr<<<1024, 256, 0, stream>>>(feat, feat_t);
  k_down<<<512, 256, 0, stream>>>(guide, luma_lr);
  k_grid<<<2048, 128, 0, stream>>>(feat_t, luma_lr, sx_raw, sy_raw, sr_raw, gridh, den);
  k_slice<<<512, 1024, 0, stream>>>((const uint4*)gridh, den, guide, out);
}